// Round 1
// baseline (104.793 us; speedup 1.0000x reference)
//
#include <hip/hip_runtime.h>
#include <hip/hip_bf16.h>

#define M_SAMP 4096
#define D_IN   100
#define HID    256
#define IN_DIM 101
#define NSQ    10000   // 100*100

typedef __attribute__((ext_vector_type(8))) short short8;
typedef __attribute__((ext_vector_type(4))) float f32x4;

// ---------------- kernel 1: W1T[j][h] = W1[h][j] ----------------
__global__ __launch_bounds__(256) void k_w1t(const float* __restrict__ W1,
                                             float* __restrict__ W1T) {
    int j = blockIdx.x;   // 0..100
    int h = threadIdx.x;  // 0..255
    W1T[j * HID + h] = W1[h * IN_DIM + j];
}

// ---------------- kernel 2: forward + grad (fp32), S2n (bf16) ----------------
// 8 samples per block, 256 threads (one per hidden unit for the z phase).
__global__ __launch_bounds__(256) void k_fwd(
        const float* __restrict__ t, const float* __restrict__ X,
        const float* __restrict__ W1, const float* __restrict__ W1T,
        const float* __restrict__ b1, const float* __restrict__ W2,
        const float* __restrict__ b2,
        float* __restrict__ u_out, float* __restrict__ dux_out,
        float* __restrict__ dut_out, __hip_bfloat16* __restrict__ S2n) {
    const int SM = 8;
    __shared__ float s_in[SM][IN_DIM];
    __shared__ float c_sh[SM][HID];   // W2_h * cos(z)
    __shared__ float us_sh[SM][HID];  // W2_h * sin(z)

    int i0 = blockIdx.x * SM;
    int tid = threadIdx.x;

    for (int idx = tid; idx < SM * IN_DIM; idx += 256) {
        int i = idx / IN_DIM, j = idx % IN_DIM;
        s_in[i][j] = (j == 0) ? t[i0 + i] : X[(size_t)(i0 + i) * D_IN + (j - 1)];
    }
    __syncthreads();

    int h = tid;
    float z[SM];
    float bb = b1[h];
#pragma unroll
    for (int i = 0; i < SM; i++) z[i] = bb;
    for (int j = 0; j < IN_DIM; j++) {
        float w = W1T[j * HID + h];   // coalesced across lanes
#pragma unroll
        for (int i = 0; i < SM; i++) z[i] += w * s_in[i][j];
    }
    float w2 = W2[h];
#pragma unroll
    for (int i = 0; i < SM; i++) {
        float sz, cz;
        sincosf(z[i], &sz, &cz);
        c_sh[i][h] = w2 * cz;
        us_sh[i][h] = w2 * sz;
        S2n[(size_t)(i0 + i) * HID + h] = __float2bfloat16(-w2 * sz);
    }
    __syncthreads();

    // reduce us_sh rows -> u
    for (int off = 128; off > 0; off >>= 1) {
        if (tid < off) {
#pragma unroll
            for (int i = 0; i < SM; i++) us_sh[i][tid] += us_sh[i][tid + off];
        }
        __syncthreads();
    }
    if (tid < SM) u_out[i0 + tid] = us_sh[tid][0] + b2[0];

    // gradient: g_j = sum_h c_h * W1[h][j]; threads 0..100 own one j each.
    if (tid < IN_DIM) {
        float acc[SM];
#pragma unroll
        for (int i = 0; i < SM; i++) acc[i] = 0.f;
        for (int hh = 0; hh < HID; hh++) {
            float w = W1[hh * IN_DIM + tid];  // coalesced across lanes
#pragma unroll
            for (int i = 0; i < SM; i++) acc[i] += c_sh[i][hh] * w;
        }
        if (tid == 0) {
            for (int i = 0; i < SM; i++) dut_out[i0 + i] = acc[i];
        } else {
            for (int i = 0; i < SM; i++)
                dux_out[(size_t)(i0 + i) * D_IN + (tid - 1)] = acc[i];
        }
    }
}

// ---------------- kernel 3: P_T[n][h] = W1x[h][j]*W1x[h][k], bf16 ----------------
__global__ __launch_bounds__(256) void k_pgen(const float* __restrict__ W1T,
                                              __hip_bfloat16* __restrict__ P) {
    int n = blockIdx.x;           // 0..9999
    int j = n / D_IN, k = n % D_IN;
    int h = threadIdx.x;
    float a = W1T[(1 + j) * HID + h];
    float b = W1T[(1 + k) * HID + h];
    P[(size_t)n * HID + h] = __float2bfloat16(a * b);
}

// ---------------- kernel 4: C[4096][10000] = S2n @ P_T^T (MFMA bf16) ----------------
#define BM 128
#define BN 128
#define BK 32
#define NBLK 79   // ceil(10000/128)

__device__ __forceinline__ int swz(int row, int chunk) {
    // byte offset into a [rows][32] bf16 tile (64 B/row), XOR-swizzled
    int b = (row << 6) + (chunk << 4);
    return b ^ ((row & 7) << 4);
}

__global__ __launch_bounds__(256) void k_gemm(
        const __hip_bfloat16* __restrict__ A,   // [4096][256] row-major
        const __hip_bfloat16* __restrict__ B,   // [10000][256] n-major (=B^T)
        float* __restrict__ C) {                // [4096][10000]
    __shared__ alignas(16) short As[BM * BK];   // 8 KB
    __shared__ alignas(16) short Bs[BN * BK];   // 8 KB

    int bid = blockIdx.x;
    int bm = bid / NBLK, bn = bid % NBLK;
    int m0 = bm * BM, n0 = bn * BN;
    int tid = threadIdx.x;
    int lane = tid & 63, wave = tid >> 6;
    int wm = wave >> 1, wn = wave & 1;   // 2x2 waves, 64x64 each

    f32x4 acc[4][4];
#pragma unroll
    for (int i = 0; i < 4; i++)
#pragma unroll
        for (int j = 0; j < 4; j++) acc[i][j] = {0.f, 0.f, 0.f, 0.f};

    const short* Ag = (const short*)A;
    const short* Bg = (const short*)B;

    for (int kt = 0; kt < 256; kt += BK) {
        __syncthreads();   // previous tile fully consumed
#pragma unroll
        for (int q = 0; q < 2; q++) {
            int idx = tid * 2 + q;          // 0..511
            int row = idx >> 2, c4 = idx & 3;
            short8 va = *(const short8*)(Ag + (size_t)(m0 + row) * HID + kt + c4 * 8);
            int nrow = n0 + row; if (nrow > NSQ - 1) nrow = NSQ - 1;  // clamp (stores guarded)
            short8 vb = *(const short8*)(Bg + (size_t)nrow * HID + kt + c4 * 8);
            *(short8*)((char*)As + swz(row, c4)) = va;
            *(short8*)((char*)Bs + swz(row, c4)) = vb;
        }
        __syncthreads();

        short8 af[4], bf[4];
        int chunk = lane >> 4;
#pragma unroll
        for (int mi = 0; mi < 4; mi++) {
            int r = wm * 64 + mi * 16 + (lane & 15);
            af[mi] = *(const short8*)((const char*)As + swz(r, chunk));
        }
#pragma unroll
        for (int ni = 0; ni < 4; ni++) {
            int r = wn * 64 + ni * 16 + (lane & 15);
            bf[ni] = *(const short8*)((const char*)Bs + swz(r, chunk));
        }
#pragma unroll
        for (int mi = 0; mi < 4; mi++)
#pragma unroll
            for (int ni = 0; ni < 4; ni++)
                acc[mi][ni] = __builtin_amdgcn_mfma_f32_16x16x32_bf16(
                    af[mi], bf[ni], acc[mi][ni], 0, 0, 0);
    }

    // epilogue: C row = m0+wm*64+mi*16+(lane>>4)*4+r, col = n0+wn*64+ni*16+(lane&15)
#pragma unroll
    for (int mi = 0; mi < 4; mi++) {
        int rbase = m0 + wm * 64 + mi * 16 + ((lane >> 4) << 2);
#pragma unroll
        for (int ni = 0; ni < 4; ni++) {
            int col = n0 + wn * 64 + ni * 16 + (lane & 15);
            if (col < NSQ) {
#pragma unroll
                for (int r = 0; r < 4; r++)
                    C[(size_t)(rbase + r) * NSQ + col] = acc[mi][ni][r];
            }
        }
    }
}

extern "C" void kernel_launch(void* const* d_in, const int* in_sizes, int n_in,
                              void* d_out, int out_size, void* d_ws, size_t ws_size,
                              hipStream_t stream) {
    const float* t  = (const float*)d_in[0];
    const float* X  = (const float*)d_in[1];
    const float* W1 = (const float*)d_in[2];
    const float* b1 = (const float*)d_in[3];
    const float* W2 = (const float*)d_in[4];
    const float* b2 = (const float*)d_in[5];

    float* out = (float*)d_out;
    float* u_out = out;                                  // 4096
    float* dux   = out + M_SAMP;                         // 409600
    float* dut   = out + M_SAMP + (size_t)M_SAMP * D_IN; // 4096
    float* H     = dut + M_SAMP;                         // 40,960,000

    char* ws = (char*)d_ws;
    float* W1T          = (float*)ws;                            // 103,424 B
    __hip_bfloat16* S2n = (__hip_bfloat16*)(ws + 131072);        // 2 MB
    __hip_bfloat16* P   = (__hip_bfloat16*)(ws + 131072 + 2097152); // 5 MB

    k_w1t<<<IN_DIM, 256, 0, stream>>>(W1, W1T);
    k_fwd<<<M_SAMP / 8, 256, 0, stream>>>(t, X, W1, W1T, b1, W2, b2,
                                          u_out, dux, dut, S2n);
    k_pgen<<<NSQ, 256, 0, stream>>>(W1T, P);
    k_gemm<<<(M_SAMP / BM) * NBLK, 256, 0, stream>>>(S2n, P, H);
}